// Round 15
// baseline (443.506 us; speedup 1.0000x reference)
//
#include <hip/hip_runtime.h>
#include <hip/hip_bf16.h>
#include <math.h>

typedef _Float16 f16x8 __attribute__((ext_vector_type(8)));
typedef _Float16 f16x4 __attribute__((ext_vector_type(4)));
typedef _Float16 f16x2 __attribute__((ext_vector_type(2)));
typedef float    f32x4 __attribute__((ext_vector_type(4)));
typedef float    f32x2 __attribute__((ext_vector_type(2)));

#define DIMD    256
#define MT      64          // rows per block
#define BT      256         // 4 waves; each wave owns 16 rows x 256 cols
#define KSTEPS  26
#define EXP_C   7.2134752044448170f   // log2(e)/TEMP, TEMP=0.2
#define LOG2E   1.4426950408889634f   // le5 = (mask-M)*LOG2E = log2(E)/5
#define INV_1MP 1.1111111111111112f   // 1/(1-P), P=0.1

static __device__ __forceinline__ f16x2 cvt_pk(float a, float b) {
    return __builtin_bit_cast(f16x2, __builtin_amdgcn_cvt_pkrtz(a, b));
}

// ---- packed-f32 VALU helpers (VOP3P) -------------------------------------
static __device__ __forceinline__ f32x2 pk_fma(f32x2 a, f32x2 b, f32x2 c) {
    f32x2 d;
    asm("v_pk_fma_f32 %0, %1, %2, %3" : "=v"(d) : "v"(a), "v"(b), "v"(c));
    return d;
}
static __device__ __forceinline__ f32x2 pk_mul(f32x2 a, f32x2 b) {
    f32x2 d;
    asm("v_pk_mul_f32 %0, %1, %2" : "=v"(d) : "v"(a), "v"(b));
    return d;
}
static __device__ __forceinline__ f32x2 pk_add(f32x2 a, f32x2 b) {
    f32x2 d;
    asm("v_pk_add_f32 %0, %1, %2" : "=v"(d) : "v"(a), "v"(b));
    return d;
}

// ---- DPP row_ror cross-lane (16-lane groups) -----------------------------
template<int CTRL>
static __device__ __forceinline__ float dpp_ror(float s) {
    return __builtin_bit_cast(float, __builtin_amdgcn_update_dpp(
        0, __builtin_bit_cast(int, s), CTRL, 0xf, 0xf, false));
}
static __device__ __forceinline__ float row16_sum(float s) {
    s += dpp_ror<0x128>(s);
    s += dpp_ror<0x124>(s);
    s += dpp_ror<0x122>(s);
    s += dpp_ror<0x121>(s);
    return s;
}
static __device__ __forceinline__ float row16_max(float m) {
    m = fmaxf(m, dpp_ror<0x128>(m));
    m = fmaxf(m, dpp_ror<0x124>(m));
    m = fmaxf(m, dpp_ror<0x122>(m));
    m = fmaxf(m, dpp_ror<0x121>(m));
    return m;
}

// ---- pre-kernel: W[c][k] fp32 -> frag-major fp16 -------------------------
__global__ __launch_bounds__(256)
void w_conv_kernel(const float* __restrict__ W, f16x8* __restrict__ ws) {
    int gid  = blockIdx.x * 256 + threadIdx.x;
    int tile = gid >> 6;
    int lane = gid & 63;
    int kt = tile >> 4, ct = tile & 15;
    int col = ct * 16 + (lane & 15);
    int k0  = kt * 32 + (lane >> 4) * 8;
    const float* wr = W + col * 256 + k0;
    float4 f01 = *(const float4*)wr;
    float4 f23 = *(const float4*)(wr + 4);
    float wv[8] = {f01.x, f01.y, f01.z, f01.w, f23.x, f23.y, f23.z, f23.w};
    f16x8 hi;
    #pragma unroll
    for (int j = 0; j < 8; ++j) hi[j] = (_Float16)wv[j];
    ws[tile * 64 + lane] = hi;
}

// ---- Kernel A: GEMM -> le5 (fp16x2 as u32, SoA by (p,cc)) ----------------
__global__ __launch_bounds__(BT, 4)
void sad_gemm_kernel(const float* __restrict__ feat,
                     const float* __restrict__ bias,
                     const f16x8* __restrict__ ws,
                     unsigned int* __restrict__ lew,
                     int N, int totThreads)
{
    __shared__ __align__(16) unsigned char smem[MT * 512];  // 32 KB

    const int tid  = threadIdx.x;
    const int lane = tid & 63;
    const long long n0 = (long long)blockIdx.x * MT;

    const float4* fvec = (const float4*)feat;
    #pragma unroll
    for (int i = 0; i < 16; ++i) {
        int flat4 = i * BT + tid;
        int row = flat4 >> 6;
        int c4  = flat4 & 63;
        long long grow = n0 + row;
        if (grow >= N) grow = N - 1;
        float4 f = fvec[grow * 64 + c4];
        f16x4 h4;
        h4[0] = (_Float16)f.x; h4[1] = (_Float16)f.y;
        h4[2] = (_Float16)f.z; h4[3] = (_Float16)f.w;
        int off = row * 512 + ((c4 * 8) ^ ((row & 7) << 4));
        *(f16x4*)(smem + off) = h4;
    }
    __syncthreads();

    f32x4 acc[16];
    #pragma unroll
    for (int ct = 0; ct < 16; ++ct) {
        float b = bias[ct * 16 + (lane & 15)];
        acc[ct] = f32x4{b, b, b, b};
    }

    const int wv    = tid >> 6;
    const int arow  = wv * 16 + (lane & 15);
    const int swzA  = (arow & 7) << 4;
    const int abase = arow * 512;
    const int kgrp  = (lane >> 4) * 16;

    #pragma unroll
    for (int kt = 0; kt < 8; ++kt) {
        int kbyte = kt * 64 + kgrp;
        f16x8 a8 = *(const f16x8*)(smem + abase + (kbyte ^ swzA));
        #pragma unroll
        for (int ct = 0; ct < 16; ++ct) {
            f16x8 bh = ws[(kt * 16 + ct) * 64 + lane];
            acc[ct] = __builtin_amdgcn_mfma_f32_16x16x32_f16(a8, bh, acc[ct], 0, 0, 0);
        }
    }

    // row max per plane -> le5 fp16x2, store SoA-coalesced
    long long gtid = (long long)blockIdx.x * BT + tid;
    #pragma unroll
    for (int p = 0; p < 4; ++p) {
        float m = acc[0][p];
        #pragma unroll
        for (int ct = 1; ct < 16; ++ct) m = fmaxf(m, acc[ct][p]);
        float M = row16_max(m);
        #pragma unroll
        for (int cc = 0; cc < 8; ++cc) {
            f16x2 le = cvt_pk((acc[2 * cc][p]     - M) * LOG2E,
                              (acc[2 * cc + 1][p] - M) * LOG2E);
            lew[(long long)(p * 8 + cc) * totThreads + gtid] =
                __builtin_bit_cast(unsigned int, le);
        }
    }
}

// ---- Kernel B: le5 -> q-form peel -> out (high occupancy, no LDS) --------
__global__ __launch_bounds__(BT, 8)
void sad_peel_kernel(const float* __restrict__ feat,
                     const unsigned int* __restrict__ lew,
                     float* __restrict__ out,
                     int N, int totThreads)
{
    const int tid  = threadIdx.x;
    const int lane = tid & 63;
    const int wv   = tid >> 6;
    const long long n0 = (long long)blockIdx.x * MT;
    const long long gtid = (long long)blockIdx.x * BT + tid;
    const f32x2 one2 = f32x2{1.0f, 1.0f};

    #pragma unroll 1
    for (int p = 0; p < 4; ++p) {
        f16x2 lp[8];
        #pragma unroll
        for (int cc = 0; cc < 8; ++cc)
            lp[cc] = __builtin_bit_cast(f16x2,
                lew[(long long)(p * 8 + cc) * totThreads + gtid]);

        f32x2 q[8];
        #pragma unroll
        for (int cc = 0; cc < 8; ++cc)
            q[cc] = f32x2{__builtin_amdgcn_exp2f(5.0f * (float)lp[cc][0]),
                          __builtin_amdgcn_exp2f(5.0f * (float)lp[cc][1])};

        #pragma unroll 1
        for (int it = 0; it < KSTEPS; ++it) {
            f32x2 s2 = pk_add(pk_add(pk_add(q[0], q[1]), pk_add(q[2], q[3])),
                              pk_add(pk_add(q[4], q[5]), pk_add(q[6], q[7])));
            float s = row16_sum(s2.x + s2.y);
            s = fmaxf(s, 1e-30f);
            float nr = -__builtin_amdgcn_rcpf(s);
            f32x2 nrv = f32x2{nr, nr};
            #pragma unroll
            for (int cc = 0; cc < 8; ++cc) {
                f32x2 r  = pk_fma(q[cc], nrv, one2);   // 1 - q/S
                f32x2 r2 = pk_mul(r, r);
                f32x2 r4 = pk_mul(r2, r2);
                f32x2 r5 = pk_mul(r4, r);
                q[cc] = pk_mul(q[cc], r5);             // q *= r^5
            }
        }

        int row = wv * 16 + (lane >> 4) * 4 + p;
        long long grow = n0 + row;
        if (grow < N) {
            const float* frow = feat + grow * 256;
            float* orow = out + grow * 256;
            #pragma unroll
            for (int cc = 0; cc < 8; ++cc) {
                #pragma unroll
                for (int h = 0; h < 2; ++h) {
                    int col = (2 * cc + h) * 16 + (lane & 15);
                    float le5 = (float)lp[cc][h];
                    float qv  = fmaxf(h ? q[cc].y : q[cc].x, 1e-38f);
                    float zz  = __builtin_amdgcn_exp2f(
                        fmaf(__builtin_amdgcn_logf(qv), 0.2f, -le5));
                    orow[col] = frow[col] * (zz * INV_1MP);
                }
            }
        }
    }
}

// ---- Fallback: r10 fused kernel (used only if ws too small) --------------
__global__ __launch_bounds__(BT, 4)
void sad_fused_kernel(const float* __restrict__ feat,
                      const float* __restrict__ bias,
                      const f16x8* __restrict__ ws,
                      float* __restrict__ out,
                      int N)
{
    __shared__ __align__(16) unsigned char smem[MT * 512];
    const int tid  = threadIdx.x;
    const int lane = tid & 63;
    const int wv   = tid >> 6;
    const long long n0 = (long long)blockIdx.x * MT;

    const float4* fvec = (const float4*)feat;
    #pragma unroll
    for (int i = 0; i < 16; ++i) {
        int flat4 = i * BT + tid;
        int row = flat4 >> 6;
        int c4  = flat4 & 63;
        long long grow = n0 + row;
        if (grow >= N) grow = N - 1;
        float4 f = fvec[grow * 64 + c4];
        f16x4 h4;
        h4[0] = (_Float16)f.x; h4[1] = (_Float16)f.y;
        h4[2] = (_Float16)f.z; h4[3] = (_Float16)f.w;
        int off = row * 512 + ((c4 * 8) ^ ((row & 7) << 4));
        *(f16x4*)(smem + off) = h4;
    }
    __syncthreads();

    f32x4 acc[16];
    #pragma unroll
    for (int ct = 0; ct < 16; ++ct) {
        float b = bias[ct * 16 + (lane & 15)];
        acc[ct] = f32x4{b, b, b, b};
    }
    const int arow  = wv * 16 + (lane & 15);
    const int swzA  = (arow & 7) << 4;
    const int abase = arow * 512;
    const int kgrp  = (lane >> 4) * 16;
    #pragma unroll
    for (int kt = 0; kt < 8; ++kt) {
        int kbyte = kt * 64 + kgrp;
        f16x8 a8 = *(const f16x8*)(smem + abase + (kbyte ^ swzA));
        #pragma unroll
        for (int ct = 0; ct < 16; ++ct) {
            f16x8 bh = ws[(kt * 16 + ct) * 64 + lane];
            acc[ct] = __builtin_amdgcn_mfma_f32_16x16x32_f16(a8, bh, acc[ct], 0, 0, 0);
        }
    }
    float M[4];
    #pragma unroll
    for (int p = 0; p < 4; ++p) {
        float m = acc[0][p];
        #pragma unroll
        for (int ct = 1; ct < 16; ++ct) m = fmaxf(m, acc[ct][p]);
        M[p] = row16_max(m);
    }
    const f32x2 one2 = f32x2{1.0f, 1.0f};
    #pragma unroll 1
    for (int p = 0; p < 4; ++p) {
        f32x2 q[8];
        #pragma unroll
        for (int cc = 0; cc < 8; ++cc) {
            q[cc] = f32x2{
                __builtin_amdgcn_exp2f((acc[2 * cc][p]     - M[p]) * EXP_C),
                __builtin_amdgcn_exp2f((acc[2 * cc + 1][p] - M[p]) * EXP_C)};
        }
        #pragma unroll 1
        for (int it = 0; it < KSTEPS; ++it) {
            f32x2 s2 = pk_add(pk_add(pk_add(q[0], q[1]), pk_add(q[2], q[3])),
                              pk_add(pk_add(q[4], q[5]), pk_add(q[6], q[7])));
            float s = row16_sum(s2.x + s2.y);
            s = fmaxf(s, 1e-30f);
            float nr = -__builtin_amdgcn_rcpf(s);
            f32x2 nrv = f32x2{nr, nr};
            #pragma unroll
            for (int cc = 0; cc < 8; ++cc) {
                f32x2 r  = pk_fma(q[cc], nrv, one2);
                f32x2 r2 = pk_mul(r, r);
                f32x2 r4 = pk_mul(r2, r2);
                f32x2 r5 = pk_mul(r4, r);
                q[cc] = pk_mul(q[cc], r5);
            }
        }
        int row = wv * 16 + (lane >> 4) * 4 + p;
        long long grow = n0 + row;
        if (grow < N) {
            int swz = (row & 7) << 4;
            float* orow = out + grow * 256;
            #pragma unroll
            for (int cc = 0; cc < 8; ++cc) {
                #pragma unroll
                for (int h = 0; h < 2; ++h) {
                    int col = (2 * cc + h) * 16 + (lane & 15);
                    float le5 = (acc[2 * cc + h][p] - M[p]) * LOG2E;
                    float qv  = fmaxf(h ? q[cc].y : q[cc].x, 1e-38f);
                    float zz  = __builtin_amdgcn_exp2f(
                        fmaf(__builtin_amdgcn_logf(qv), 0.2f, -le5));
                    int off = row * 512 + ((col * 2) ^ swz);
                    float fval = (float)(*(const _Float16*)(smem + off));
                    orow[col] = fval * (zz * INV_1MP);
                }
            }
        }
    }
}

extern "C" void kernel_launch(void* const* d_in, const int* in_sizes, int n_in,
                              void* d_out, int out_size, void* d_ws, size_t ws_size,
                              hipStream_t stream) {
    const float* feat = (const float*)d_in[0];
    const float* W    = (const float*)d_in[1];
    const float* bias = (const float*)d_in[2];
    float* out = (float*)d_out;
    int N = in_sizes[0] / DIMD;
    int grid = (N + MT - 1) / MT;
    long long totThreads = (long long)grid * BT;

    // W frags at ws[0, 128KB); le5 buffer at ws + 128KB (needs ~154 MB)
    w_conv_kernel<<<32, 256, 0, stream>>>(W, (f16x8*)d_ws);

    size_t need = (size_t)131072 + (size_t)totThreads * 32u * 4u;
    if (ws_size >= need) {
        unsigned int* lew = (unsigned int*)((unsigned char*)d_ws + 131072);
        sad_gemm_kernel<<<grid, BT, 0, stream>>>(feat, bias, (const f16x8*)d_ws,
                                                 lew, N, (int)totThreads);
        sad_peel_kernel<<<grid, BT, 0, stream>>>(feat, lew, out, N, (int)totThreads);
    } else {
        sad_fused_kernel<<<grid, BT, 0, stream>>>(feat, bias, (const f16x8*)d_ws,
                                                  out, N);
    }
}

// Round 16
// 329.856 us; speedup vs baseline: 1.3445x; 1.3445x over previous
//
#include <hip/hip_runtime.h>
#include <hip/hip_bf16.h>
#include <math.h>

typedef _Float16 f16x8 __attribute__((ext_vector_type(8)));
typedef _Float16 f16x4 __attribute__((ext_vector_type(4)));
typedef _Float16 f16x2 __attribute__((ext_vector_type(2)));
typedef float    f32x4 __attribute__((ext_vector_type(4)));
typedef float    f32x2 __attribute__((ext_vector_type(2)));

#define DIMD    256
#define MT      64          // rows per block
#define BT      256         // 4 waves; each wave owns 16 rows x 256 cols
#define KSTEPS  26
#define LOG2E   1.4426950408889634f   // le5 = mask*LOG2E = log2(E)/5 (no max-sub)
#define INV_1MP 1.1111111111111112f   // 1/(1-P), P=0.1

static __device__ __forceinline__ f16x2 cvt_pk(float a, float b) {
    return __builtin_bit_cast(f16x2, __builtin_amdgcn_cvt_pkrtz(a, b));
}

// ---- packed-f32 VALU helpers (VOP3P) -------------------------------------
static __device__ __forceinline__ f32x2 pk_fma(f32x2 a, f32x2 b, f32x2 c) {
    f32x2 d;
    asm("v_pk_fma_f32 %0, %1, %2, %3" : "=v"(d) : "v"(a), "v"(b), "v"(c));
    return d;
}
static __device__ __forceinline__ f32x2 pk_mul(f32x2 a, f32x2 b) {
    f32x2 d;
    asm("v_pk_mul_f32 %0, %1, %2" : "=v"(d) : "v"(a), "v"(b));
    return d;
}
static __device__ __forceinline__ f32x2 pk_add(f32x2 a, f32x2 b) {
    f32x2 d;
    asm("v_pk_add_f32 %0, %1, %2" : "=v"(d) : "v"(a), "v"(b));
    return d;
}

// ---- DPP row_ror cross-lane (16-lane groups) -----------------------------
template<int CTRL>
static __device__ __forceinline__ float dpp_ror(float s) {
    return __builtin_bit_cast(float, __builtin_amdgcn_update_dpp(
        0, __builtin_bit_cast(int, s), CTRL, 0xf, 0xf, false));
}
static __device__ __forceinline__ float row16_sum(float s) {
    s += dpp_ror<0x128>(s);
    s += dpp_ror<0x124>(s);
    s += dpp_ror<0x122>(s);
    s += dpp_ror<0x121>(s);
    return s;
}

// ---- pre-kernel: W[c][k] fp32 -> frag-major fp16 -------------------------
__global__ __launch_bounds__(256)
void w_conv_kernel(const float* __restrict__ W, f16x8* __restrict__ ws) {
    int gid  = blockIdx.x * 256 + threadIdx.x;
    int tile = gid >> 6;
    int lane = gid & 63;
    int kt = tile >> 4, ct = tile & 15;
    int col = ct * 16 + (lane & 15);
    int k0  = kt * 32 + (lane >> 4) * 8;
    const float* wr = W + col * 256 + k0;
    float4 f01 = *(const float4*)wr;
    float4 f23 = *(const float4*)(wr + 4);
    float wv[8] = {f01.x, f01.y, f01.z, f01.w, f23.x, f23.y, f23.z, f23.w};
    f16x8 hi;
    #pragma unroll
    for (int j = 0; j < 8; ++j) hi[j] = (_Float16)wv[j];
    ws[tile * 64 + lane] = hi;
}

// GEMM over one 64-col chunk (ct = 4C..4C+3): acc is only 16 regs, then
// immediately compressed to fp16 le5 (no row max needed: |mask| <= ~7 so
// E = exp2(mask*5*LOG2E) stays within f32 range without shifting).
#define GEMM_CHUNK(C, LE)                                                     \
{                                                                             \
    f32x4 acc[4];                                                             \
    _Pragma("unroll")                                                         \
    for (int t = 0; t < 4; ++t) {                                             \
        float b = bias[(4 * (C) + t) * 16 + (lane & 15)];                     \
        acc[t] = f32x4{b, b, b, b};                                           \
    }                                                                         \
    _Pragma("unroll")                                                         \
    for (int kt = 0; kt < 8; ++kt) {                                          \
        int kbyte = kt * 64 + kgrp;                                           \
        f16x8 a8 = *(const f16x8*)(smem + abase + (kbyte ^ swzA));            \
        _Pragma("unroll")                                                     \
        for (int t = 0; t < 4; ++t) {                                         \
            f16x8 bh = ws[(kt * 16 + 4 * (C) + t) * 64 + lane];               \
            acc[t] = __builtin_amdgcn_mfma_f32_16x16x32_f16(a8, bh,           \
                                                            acc[t], 0, 0, 0); \
        }                                                                     \
    }                                                                         \
    _Pragma("unroll")                                                         \
    for (int p = 0; p < 4; ++p) {                                             \
        LE[p][0] = cvt_pk(acc[0][p] * LOG2E, acc[1][p] * LOG2E);              \
        LE[p][1] = cvt_pk(acc[2][p] * LOG2E, acc[3][p] * LOG2E);              \
        asm volatile("" : "+v"(LE[p][0]), "+v"(LE[p][1]));                    \
    }                                                                         \
}

// One plane's peel: literal P only (all indexing compile-time static).
#define PEEL_PLANE(P)                                                         \
{                                                                             \
    f16x2 lp[8] = {le0[P][0], le0[P][1], le1[P][0], le1[P][1],                \
                   le2[P][0], le2[P][1], le3[P][0], le3[P][1]};               \
    f32x2 q[8];                                                               \
    _Pragma("unroll")                                                         \
    for (int cc = 0; cc < 8; ++cc)                                            \
        q[cc] = f32x2{__builtin_amdgcn_exp2f(5.0f * (float)lp[cc][0]),        \
                      __builtin_amdgcn_exp2f(5.0f * (float)lp[cc][1])};       \
    _Pragma("unroll 1")                                                       \
    for (int it = 0; it < KSTEPS; ++it) {                                     \
        f32x2 s2 = pk_add(pk_add(pk_add(q[0], q[1]), pk_add(q[2], q[3])),     \
                          pk_add(pk_add(q[4], q[5]), pk_add(q[6], q[7])));    \
        float s = row16_sum(s2.x + s2.y);                                     \
        s = fmaxf(s, 1e-30f);                                                 \
        float nr = -__builtin_amdgcn_rcpf(s);                                 \
        f32x2 nrv = f32x2{nr, nr};                                            \
        _Pragma("unroll")                                                     \
        for (int cc = 0; cc < 8; ++cc) {                                      \
            f32x2 r  = pk_fma(q[cc], nrv, one2);   /* 1 - q/S   */            \
            f32x2 r2 = pk_mul(r, r);                                          \
            f32x2 r4 = pk_mul(r2, r2);                                        \
            f32x2 r5 = pk_mul(r4, r);                                         \
            q[cc] = pk_mul(q[cc], r5);             /* q *= r^5  */            \
        }                                                                     \
    }                                                                         \
    int row = wv * 16 + (lane >> 4) * 4 + (P);                                \
    long long grow = n0 + row;                                                \
    if (grow < N) {                                                           \
        int swz = (row & 7) << 4;                                             \
        float* orow = out + grow * 256;                                       \
        _Pragma("unroll")                                                     \
        for (int cc = 0; cc < 8; ++cc) {                                      \
            _Pragma("unroll")                                                 \
            for (int h = 0; h < 2; ++h) {                                     \
                int col = (2 * cc + h) * 16 + (lane & 15);                    \
                float le5 = (float)lp[cc][h];                                 \
                float qv  = fmaxf(h ? q[cc].y : q[cc].x, 1e-38f);             \
                float zz  = __builtin_amdgcn_exp2f(                           \
                    fmaf(__builtin_amdgcn_logf(qv), 0.2f, -le5));             \
                int off = row * 512 + ((col * 2) ^ swz);                      \
                float fval = (float)(*(const _Float16*)(smem + off));         \
                orow[col] = fval * (zz * INV_1MP);                            \
            }                                                                 \
        }                                                                     \
    }                                                                         \
}                                                                             \
asm volatile("" ::: "memory");

// ---- main fused kernel ----------------------------------------------------
// LDS: A fp16 [64 rows][256 cols], 32 KB (5 blocks/CU = 160 KiB exactly),
// byte-XOR swizzle: byte = row*512 + ((col*2) ^ ((row&7)<<4))
__global__ __launch_bounds__(BT, 5)
void sad_mfma_kernel(const float* __restrict__ feat,
                     const float* __restrict__ bias,
                     const f16x8* __restrict__ ws,
                     float* __restrict__ out,
                     int N)
{
    __shared__ __align__(16) unsigned char smem[MT * 512];  // 32 KB

    const int tid  = threadIdx.x;
    const int lane = tid & 63;
    const int wv   = tid >> 6;           // wave 0..3, owns rows wv*16..+15
    const long long n0 = (long long)blockIdx.x * MT;

    // ---- stage 64 feature rows -> fp16 LDS (swizzled) ----
    const float4* fvec = (const float4*)feat;
    #pragma unroll
    for (int i = 0; i < 16; ++i) {
        int flat4 = i * BT + tid;
        int row = flat4 >> 6;
        int c4  = flat4 & 63;
        long long grow = n0 + row;
        if (grow >= N) grow = N - 1;
        float4 f = fvec[grow * 64 + c4];
        f16x4 h4;
        h4[0] = (_Float16)f.x; h4[1] = (_Float16)f.y;
        h4[2] = (_Float16)f.z; h4[3] = (_Float16)f.w;
        int off = row * 512 + ((c4 * 8) ^ ((row & 7) << 4));
        *(f16x4*)(smem + off) = h4;
    }
    __syncthreads();

    const int arow  = wv * 16 + (lane & 15);
    const int swzA  = (arow & 7) << 4;
    const int abase = arow * 512;
    const int kgrp  = (lane >> 4) * 16;

    // ---- GEMM in 4 col-chunks; acc never exceeds 16 regs ----
    f16x2 le0[4][2], le1[4][2], le2[4][2], le3[4][2];
    GEMM_CHUNK(0, le0)
    asm volatile("" ::: "memory");
    GEMM_CHUNK(1, le1)
    asm volatile("" ::: "memory");
    GEMM_CHUNK(2, le2)
    asm volatile("" ::: "memory");
    GEMM_CHUNK(3, le3)
    asm volatile("" ::: "memory");

    const f32x2 one2 = f32x2{1.0f, 1.0f};

    // ---- four explicitly-sequenced plane peels (q-form, pk-f32) ----------
    PEEL_PLANE(0)
    PEEL_PLANE(1)
    PEEL_PLANE(2)
    PEEL_PLANE(3)
}

extern "C" void kernel_launch(void* const* d_in, const int* in_sizes, int n_in,
                              void* d_out, int out_size, void* d_ws, size_t ws_size,
                              hipStream_t stream) {
    const float* feat = (const float*)d_in[0];
    const float* W    = (const float*)d_in[1];
    const float* bias = (const float*)d_in[2];
    float* out = (float*)d_out;
    int N = in_sizes[0] / DIMD;

    // 1) W -> frag-major fp16 in workspace (128 KB)
    w_conv_kernel<<<32, 256, 0, stream>>>(W, (f16x8*)d_ws);

    // 2) fused chunked-GEMM + q-form peeling, 5 blocks/CU
    int grid = (N + MT - 1) / MT;
    sad_mfma_kernel<<<grid, BT, 0, stream>>>(feat, bias, (const f16x8*)d_ws, out, N);
}